// Round 1
// 551.823 us; speedup vs baseline: 1.0596x; 1.0596x over previous
//
#include <hip/hip_runtime.h>
#include <math.h>

// SelfContact: v2v_min[b,j] = min_i ( geomask[i,j] ? sq[b,i]+sq[b,j]-2*dot(v[b,i],v[b,j]) : inf )
// in_contact[b,j] = v2v_min[b,j] < 0.02^2
//
// Numerics mirror the NumPy fp32 reference exactly: separate mul/add (no FMA)
// via __fmul_rn/__fadd_rn/__fsub_rn; 2*dot folded into pre-doubled column
// coords (x2 scaling commutes with round-to-nearest — bitwise equal).
//
// R3: symmetry — upper-triangle tiles only; col-min in registers, row-min via
//     DPP wave reduce (mask traffic 439 -> ~274 MB).
// R4 FAILED: launch_bounds(256,3) capped VGPR at 84 < ~130 needed -> 2.7 GB
//     scratch spill traffic.
// R5: NC=4 footprint, uniform 1044-tile upper-triangle grid, batched mask loads.
// R6 (this round): WORKSPACE-FREE. rocprof showed the timed region is ~93%
//     harness workspace poison (2x 1.756 GB fillBufferAligned = ~548 us of the
//     584.7 us total; our kernels ~40 us, absent from top-5 dispatches).
//     Experiment: drop d_ws entirely — partial mins go through device-scope
//     atomicMin on a monotone uint encoding of float, straight into d_out.
//     Exact same min (order-isomorphic encoding, min is order-insensitive),
//     so numerics are bit-identical to the two-pass version.

#define NV   10475
#define NB   2
#define BLK  256
#define NC   4                          // columns per thread
#define CPB  (BLK * NC)                 // 1024 columns per tile
#define JB   ((NV + CPB - 1) / CPB)     // 11 column tiles
#define CH   64                         // rows per tile
#define RCT  ((NV + CH - 1) / CH)       // 164 row chunks
#define RU   4                          // row unroll
#define NTILES 1044                     // sum over jb of (jmax/CH + 1)

// ---- monotone float<->uint order-isomorphism (exact, bijective) ----
// f >= 0: key = bits | 0x80000000  (top bit was 0)
// f <  0: key = ~bits
// key order (unsigned) == float order; min preserved exactly.
__device__ __forceinline__ unsigned enc(float f) {
    unsigned u = __float_as_uint(f);
    return u ^ (unsigned)(((int)u >> 31) | (int)0x80000000);
}
__device__ __forceinline__ float dec(unsigned u) {
    unsigned m = ((int)u < 0) ? 0x80000000u : 0xFFFFFFFFu;
    return __uint_as_float(u ^ m);
}
#define ENC_INF 0xFF800000u             // enc(+inf)

__device__ __forceinline__ float sq_nofma(float x, float y, float z) {
    return __fadd_rn(__fadd_rn(__fmul_rn(x, x), __fmul_rn(y, y)), __fmul_rn(z, z));
}

template <int CTRL>
__device__ __forceinline__ float dppmin(float v) {
    int s = __builtin_amdgcn_update_dpp(__float_as_int(v), __float_as_int(v),
                                        CTRL, 0xF, 0xF, false);
    return fminf(v, __int_as_float(s));
}

// Full-wave (64-lane) min; result valid in lane 63. All lanes active.
__device__ __forceinline__ float wave_min_to_lane63(float v) {
    v = dppmin<0x111>(v);  // row_shr:1
    v = dppmin<0x112>(v);  // row_shr:2
    v = dppmin<0x114>(v);  // row_shr:4
    v = dppmin<0x118>(v);  // row_shr:8
    v = dppmin<0x142>(v);  // row_bcast:15
    v = dppmin<0x143>(v);  // row_bcast:31 -> lane 63 = wave min
    return v;
}

__global__ __launch_bounds__(BLK) void sc_init(unsigned* __restrict__ outmin) {
    int idx = blockIdx.x * BLK + threadIdx.x;
    if (idx < NB * NV) outmin[idx] = ENC_INF;
}

__global__ __launch_bounds__(BLK) void sc_partial_atomic(
    const float* __restrict__ verts,    // [NB, NV, 3]
    const int*   __restrict__ gmask,    // [NV, NV]
    unsigned*    __restrict__ outmin)   // [NB, NV] encoded running mins
{
    __shared__ float4 sv[CH * NB];      // staged row verts: (x,y,z,sq) per batch
    __shared__ float  rmin[CH][4][NB];  // per-row per-wave row-min

    const int tid = threadIdx.x;
    const int wv  = tid >> 6;

    // ---- uniform upper-triangle tile enumeration (cum tiles per jb) ----
    int t = blockIdx.x;
    int jb, rcb;
    if      (t <  16) { jb = 0;  rcb = t;       }
    else if (t <  48) { jb = 1;  rcb = t -  16; }
    else if (t <  96) { jb = 2;  rcb = t -  48; }
    else if (t < 160) { jb = 3;  rcb = t -  96; }
    else if (t < 240) { jb = 4;  rcb = t - 160; }
    else if (t < 336) { jb = 5;  rcb = t - 240; }
    else if (t < 448) { jb = 6;  rcb = t - 336; }
    else if (t < 576) { jb = 7;  rcb = t - 448; }
    else if (t < 720) { jb = 8;  rcb = t - 576; }
    else if (t < 880) { jb = 9;  rcb = t - 720; }
    else              { jb = 10; rcb = t - 880; }

    const int j0    = jb * CPB;
    const int jmax  = (j0 + CPB - 1 < NV - 1) ? (j0 + CPB - 1) : (NV - 1);
    const int r0    = rcb * CH;
    const int nrows = (CH < jmax + 1 - r0) ? CH : (jmax + 1 - r0);
    const int nr4   = (nrows + 3) & ~3;

    // ---- stage row vertices (+sq); rows past jmax clamp to jmax (benign) ----
    for (int k = tid; k < nr4 * NB; k += BLK) {
        int rr = k >> 1, b = k & 1;
        int row = r0 + rr; if (row > jmax) row = jmax;
        const float* vp = verts + ((size_t)b * NV + row) * 3;
        float x = vp[0], y = vp[1], z = vp[2];
        sv[rr * NB + b] = make_float4(x, y, z, sq_nofma(x, y, z));
    }
    __syncthreads();

    // ---- my NC columns (stride-BLK so every mask load is wave-coalesced) ----
    int  cols[NC];
    bool cval[NC];
    float cx2[NB][NC], cy2[NB][NC], cz2[NB][NC], cs[NB][NC];
#pragma unroll
    for (int c = 0; c < NC; ++c) {
        int col = j0 + tid + c * BLK;
        cval[c] = (col < NV);
        cols[c] = cval[c] ? col : (NV - 1);
#pragma unroll
        for (int b = 0; b < NB; ++b) {
            const float* vp = verts + ((size_t)b * NV + cols[c]) * 3;
            float x = vp[0], y = vp[1], z = vp[2];
            cx2[b][c] = __fmul_rn(2.0f, x);
            cy2[b][c] = __fmul_rn(2.0f, y);
            cz2[b][c] = __fmul_rn(2.0f, z);
            cs[b][c]  = sq_nofma(x, y, z);
        }
    }

    float mn[NB][NC];
#pragma unroll
    for (int b = 0; b < NB; ++b)
#pragma unroll
        for (int c = 0; c < NC; ++c) mn[b][c] = __builtin_inff();

#define ROW_BODY(LR, MKR)                                                      \
    {                                                                          \
        int lrr = (LR);                                                        \
        float4 a0 = sv[lrr * NB + 0];                                          \
        float4 a1 = sv[lrr * NB + 1];                                          \
        float rf0 = __builtin_inff(), rf1 = __builtin_inff();                  \
        _Pragma("unroll")                                                      \
        for (int c = 0; c < NC; ++c) {                                         \
            bool act = cval[c] && (MKR[c] != 0);                               \
            float d0 = __fadd_rn(__fadd_rn(__fmul_rn(a0.x, cx2[0][c]),         \
                                           __fmul_rn(a0.y, cy2[0][c])),        \
                                 __fmul_rn(a0.z, cz2[0][c]));                  \
            float v0 = __fsub_rn(__fadd_rn(a0.w, cs[0][c]), d0);               \
            float t0 = act ? v0 : __builtin_inff();                            \
            mn[0][c] = fminf(mn[0][c], t0);                                    \
            rf0      = fminf(rf0, t0);                                         \
            float d1 = __fadd_rn(__fadd_rn(__fmul_rn(a1.x, cx2[1][c]),         \
                                           __fmul_rn(a1.y, cy2[1][c])),        \
                                 __fmul_rn(a1.z, cz2[1][c]));                  \
            float v1 = __fsub_rn(__fadd_rn(a1.w, cs[1][c]), d1);               \
            float t1 = act ? v1 : __builtin_inff();                            \
            mn[1][c] = fminf(mn[1][c], t1);                                    \
            rf1      = fminf(rf1, t1);                                         \
        }                                                                      \
        rf0 = wave_min_to_lane63(rf0);                                         \
        rf1 = wave_min_to_lane63(rf1);                                         \
        if ((tid & 63) == 63) {                                                \
            rmin[lrr][wv][0] = rf0;                                            \
            rmin[lrr][wv][1] = rf1;                                            \
        }                                                                      \
    }

    // ---- main loop: RU rows/step, all 16 mask loads batched before compute ----
    for (int lr = 0; lr < nr4; lr += RU) {
        int mk[RU][NC];
#pragma unroll
        for (int r = 0; r < RU; ++r) {
            int row = r0 + lr + r; if (row > jmax) row = jmax;
            const int* grow = gmask + (size_t)row * NV;
#pragma unroll
            for (int c = 0; c < NC; ++c) mk[r][c] = grow[cols[c]];
        }
#pragma unroll
        for (int r = 0; r < RU; ++r)
            ROW_BODY(lr + r, mk[r]);
    }
#undef ROW_BODY

    __syncthreads();

    // ---- row-min partials -> device-scope atomicMin into out ----
    for (int k = tid; k < nrows * NB; k += BLK) {
        int rr = k >> 1, b = k & 1;
        float m = fminf(fminf(rmin[rr][0][b], rmin[rr][1][b]),
                        fminf(rmin[rr][2][b], rmin[rr][3][b]));
        atomicMin(&outmin[(size_t)b * NV + (r0 + rr)], enc(m));
    }

    // ---- col-min partials -> atomicMin ----
#pragma unroll
    for (int c = 0; c < NC; ++c) {
        if (cval[c]) {
            atomicMin(&outmin[cols[c]], enc(mn[0][c]));
            atomicMin(&outmin[(size_t)NV + cols[c]], enc(mn[1][c]));
        }
    }
}

__global__ __launch_bounds__(BLK) void sc_finalize(
    unsigned* __restrict__ outmin,      // [NB*NV] encoded mins (in-place decode)
    float*    __restrict__ out)         // [NB*NV] mins then [NB*NV] contact
{
    int idx = blockIdx.x * BLK + threadIdx.x;
    if (idx >= NB * NV) return;
    float m = dec(outmin[idx]);
    out[idx] = m;
    out[NB * NV + idx] = ((double)m < 0.02 * 0.02) ? 1.0f : 0.0f;
}

extern "C" void kernel_launch(void* const* d_in, const int* in_sizes, int n_in,
                              void* d_out, int out_size, void* d_ws, size_t ws_size,
                              hipStream_t stream) {
    const float* verts = (const float*)d_in[0];
    const int*   gmask = (const int*)d_in[1];
    float*    out    = (float*)d_out;
    unsigned* outmin = (unsigned*)d_out;   // first NB*NV words double as encoded-min accumulator
    (void)d_ws; (void)ws_size;             // workspace intentionally UNUSED (R6 experiment)

    int nred = (NB * NV + BLK - 1) / BLK;
    sc_init<<<nred, dim3(BLK), 0, stream>>>(outmin);
    sc_partial_atomic<<<NTILES, dim3(BLK), 0, stream>>>(verts, gmask, outmin);
    sc_finalize<<<nred, dim3(BLK), 0, stream>>>(outmin, out);
}